// Round 12
// baseline (708.683 us; speedup 1.0000x reference)
//
#include <hip/hip_runtime.h>

// LSTM_Critic: T=512, B=256, D_IN=64, H=128. Round-12 = R11 (best: 606us --
// R4 schedule + input-part MFMAs software-pipelined across the barrier) + ONE
// change: LIGHT per-step barriers. __syncthreads lowers to
// "s_waitcnt vmcnt(0) lgkmcnt(0); s_barrier" -- the vmcnt(0) drains the
// in-flight slab/x prefetches (t+2 depth) and deferred slab stores EVERY
// step. The h double-buffer hazard only needs LDS visibility:
// "s_waitcnt lgkmcnt(0); s_barrier". Global ordering is only needed at group
// boundaries (producer release needs store drain; consumer acquire needs
// buffer_inv completion) -> full __syncthreads kept at lt==0, light barrier
// for the other 15/16 steps. Poll path gets an explicit vmcnt(0) so the
// acquire's cache-inv completes before the next barrier.

#define T_STEPS 512
#define BATCH   256
#define DIN     64
#define GROUP   16
#define NGRP    (T_STEPS / GROUP)

typedef _Float16 half8 __attribute__((ext_vector_type(8)));
typedef float    f32x4 __attribute__((ext_vector_type(4)));

#define LOG2E  1.44269504088896f
#define LOG2E2 2.88539008177793f

// ---- ws layout (fp16 element offsets unless noted) ----
#define WH_IH0 0          // [512][64]
#define WH_HH0 32768      // [512][128]
#define WH_IH1 98304      // [512][128]
#define WH_HH1 163840     // [512][128]
// mode 2: + fp16 x + slab + flags
#define WH_X2     229376                   // 8388608 halfs
#define WH_SLAB2  8617984                  // 16777216 halfs (512*16*2048)
#define WB_FLAG2  50790400                 // byte offset, 8192 ints reserved
#define WS2_TOTAL 50823168
// mode 1: + slab + flags (x stays fp32 from input)
#define WH_SLAB1  229376
#define WB_FLAG1  34013184
#define WS1_TOTAL 34045952
// mode 0 (monolithic): optional fp16 x at WH_X2
#define WS0XH_TOTAL ((size_t)(WH_X2 + 8388608) * 2)

__global__ void prep_weights(const float* __restrict__ wih0,
                             const float* __restrict__ whh0,
                             const float* __restrict__ wih1,
                             const float* __restrict__ whh1,
                             _Float16* __restrict__ ws) {
    int idx = blockIdx.x * 256 + threadIdx.x;   // 229376 total
    float v; int row;
    if (idx < 32768)       { row = idx >> 6;             v = wih0[idx]; }
    else if (idx < 98304)  { row = (idx - 32768) >> 7;   v = whh0[idx - 32768]; }
    else if (idx < 163840) { row = (idx - 98304) >> 7;   v = wih1[idx - 98304]; }
    else                   { row = (idx - 163840) >> 7;  v = whh1[idx - 163840]; }
    // gate chunk 2 (g) uses tanh -> scale 2*log2e; others sigmoid -> log2e
    float sc = ((row >> 7) == 2) ? LOG2E2 : LOG2E;
    ws[idx] = (_Float16)(v * sc);
}

__global__ void prep_state(const float* __restrict__ s, _Float16* __restrict__ d) {
    int i = (blockIdx.x * 256 + threadIdx.x) * 8;   // 8388608 elements
    f32x4 a = *(const f32x4*)(s + i);
    f32x4 b = *(const f32x4*)(s + i + 4);
    half8 h;
    h[0]=(_Float16)a[0]; h[1]=(_Float16)a[1]; h[2]=(_Float16)a[2]; h[3]=(_Float16)a[3];
    h[4]=(_Float16)b[0]; h[5]=(_Float16)b[1]; h[6]=(_Float16)b[2]; h[7]=(_Float16)b[3];
    *(half8*)(d + i) = h;
}

// activations on pre-scaled gate values
__device__ __forceinline__ float sig2(float y) {        // y = x*log2e
    return __builtin_amdgcn_rcpf(1.0f + __builtin_amdgcn_exp2f(-y));
}
__device__ __forceinline__ float tanh2(float y2) {      // y2 = x*2*log2e
    return 1.0f - 2.0f * __builtin_amdgcn_rcpf(1.0f + __builtin_amdgcn_exp2f(y2));
}
__device__ __forceinline__ float tanh_c(float c) {      // c unscaled
    return 1.0f - 2.0f * __builtin_amdgcn_rcpf(1.0f + __builtin_amdgcn_exp2f(c * LOG2E2));
}

// LDS-visibility-only barrier: drains lgkmcnt (hdb reads/writes) but leaves
// slab stores and global prefetches in flight across the step boundary.
__device__ __forceinline__ void light_barrier() {
    asm volatile("s_waitcnt lgkmcnt(0)" ::: "memory");
    __builtin_amdgcn_s_barrier();
}

// =====================  pipelined kernel  =====================
// LDS (halfs): wrec[512][128] swizzled = 65536 | hdb[2][16][128] = 4096 | woutl[128]
#define PIPE_LDS_BYTES ((65536 + 4096 + 128) * 2)

template<bool XH>
__global__ __launch_bounds__(512, 1) void lstm_pipe(
        const float* __restrict__ state32, const _Float16* __restrict__ wsw,
        const float* __restrict__ b_ih0, const float* __restrict__ b_hh0,
        const float* __restrict__ b_ih1, const float* __restrict__ b_hh1,
        const float* __restrict__ w_out, const float* __restrict__ b_out,
        _Float16* __restrict__ slab, int* __restrict__ flags,
        const _Float16* __restrict__ xh, float* __restrict__ out) {
    extern __shared__ _Float16 lds[];
    _Float16* wrec  = lds;            // recurrent weights (whh0 / whh1), swizzled
    _Float16* hdb   = lds + 65536;    // h double-buffer [2][16][128], swizzled
    _Float16* woutl = lds + 69632;    // head weights (consumer)

    const int tid  = threadIdx.x;
    const int w    = tid >> 6;
    const int lane = tid & 63;
    const int col  = lane & 15;
    const int quad = lane >> 4;
    const bool producer = blockIdx.x < 16;
    const int tile = blockIdx.x & 15;
    const int rowbase = tile * 16;
    const int j0 = w * 16 + col;

    // ---- one-time LDS init ----
    const _Float16* wrg = wsw + (producer ? WH_HH0 : WH_HH1);
    #pragma unroll
    for (int it = 0; it < 16; ++it) {
        int flat = (it * 512 + tid) * 8;
        int r = flat >> 7, chunk = (flat >> 3) & 15;
        *(half8*)(wrec + r * 128 + ((chunk ^ (r & 15)) * 8)) = *(const half8*)(wrg + flat);
    }
    {
        half8 z;
        #pragma unroll
        for (int jj = 0; jj < 8; ++jj) z[jj] = (_Float16)0.0f;
        *(half8*)(hdb + tid * 8) = z;   // 512*8 = 4096 halfs
    }
    if (!producer && tid < 128) woutl[tid] = (_Float16)w_out[tid];

    // ---- resident input-side B-frags + scaled biases ----
    half8 wresf[4][4];   // producer uses [nt][0..1] (wih0), consumer [nt][0..3] (wih1)
    float bias[4];
    #pragma unroll
    for (int nt = 0; nt < 4; ++nt) {
        int j = nt * 128 + j0;
        float sc = (nt == 2) ? LOG2E2 : LOG2E;
        if (producer) {
            #pragma unroll
            for (int kt = 0; kt < 2; ++kt)
                wresf[nt][kt] = *(const half8*)(wsw + WH_IH0 + j * 64 + kt * 32 + quad * 8);
            bias[nt] = (b_ih0[j] + b_hh0[j]) * sc;
        } else {
            #pragma unroll
            for (int kt = 0; kt < 4; ++kt)
                wresf[nt][kt] = *(const half8*)(wsw + WH_IH1 + j * 128 + kt * 32 + quad * 8);
            bias[nt] = (b_ih1[j] + b_hh1[j]) * sc;
        }
    }
    const float bout = b_out[0];

    // swizzled-address precompute (R2-verified, 0 bank conflicts)
    int swz[4], hoff[4], w0off[4];
    #pragma unroll
    for (int kt = 0; kt < 4; ++kt) {
        swz[kt]  = ((kt * 4 + quad) ^ col) * 8;
        hoff[kt] = col * 128 + swz[kt];
    }
    #pragma unroll
    for (int i = 0; i < 4; ++i) {
        int row = quad * 4 + i;
        w0off[i] = row * 128 + (((2 * w + (col >> 3)) ^ row) * 8) + (col & 7);
    }
    float cc[4] = {0.f, 0.f, 0.f, 0.f};

    __syncthreads();

    if (producer) {
        // ================= layer-0 producer =================
        const _Float16* xph = xh + (size_t)(rowbase + col) * DIN + quad * 8;
        const float*    xpf = state32 + (size_t)(rowbase + col) * DIN + quad * 8;

        // pre-loop: accI(0) = bias + x(0)-part; buffer x(1)
        half8 bx0, bx1;                      // XH buffer holding x(t+1)
        f32x4 bf0, bf1, bf2, bf3;            // non-XH buffer
        f32x4 accI[4];
        {
            half8 a0, a1v;
            if constexpr (XH) {
                a0  = *(const half8*)(xph);
                a1v = *(const half8*)(xph + 32);
            } else {
                f32x4 t0 = *(const f32x4*)(xpf),      t1 = *(const f32x4*)(xpf + 4);
                f32x4 t2 = *(const f32x4*)(xpf + 32), t3 = *(const f32x4*)(xpf + 36);
                #pragma unroll
                for (int jj = 0; jj < 4; ++jj) {
                    a0[jj]  = (_Float16)t0[jj]; a0[jj+4]  = (_Float16)t1[jj];
                    a1v[jj] = (_Float16)t2[jj]; a1v[jj+4] = (_Float16)t3[jj];
                }
            }
            #pragma unroll
            for (int nt = 0; nt < 4; ++nt) {
                f32x4 b = {bias[nt], bias[nt], bias[nt], bias[nt]};
                accI[nt] = b;
            }
            #pragma unroll
            for (int nt = 0; nt < 4; ++nt)
                accI[nt] = __builtin_amdgcn_mfma_f32_16x16x32_f16(a0, wresf[nt][0], accI[nt], 0, 0, 0);
            #pragma unroll
            for (int nt = 0; nt < 4; ++nt)
                accI[nt] = __builtin_amdgcn_mfma_f32_16x16x32_f16(a1v, wresf[nt][1], accI[nt], 0, 0, 0);
            // buffer x(1)
            if constexpr (XH) {
                bx0 = *(const half8*)(xph + BATCH * DIN);
                bx1 = *(const half8*)(xph + BATCH * DIN + 32);
            } else {
                bf0 = *(const f32x4*)(xpf + BATCH * DIN);
                bf1 = *(const f32x4*)(xpf + BATCH * DIN + 4);
                bf2 = *(const f32x4*)(xpf + BATCH * DIN + 32);
                bf3 = *(const f32x4*)(xpf + BATCH * DIN + 36);
            }
        }
        _Float16 hh[4];   // held h(t-1), stored at top of step t

        #pragma unroll 2
        for (int t = 0; t < T_STEPS; ++t) {
            const int pbo = (t & 1) * 2048, cbo = pbo ^ 2048;
            const int lt = t & (GROUP - 1);
            if (lt == 0) {
                __syncthreads();   // full: drains all waves' slab stores
                // group (t/GROUP - 1) fully stored + drained -> publish
                if (t > 0 && tid == 0)
                    __hip_atomic_store(flags + (t / GROUP - 1) * 16 + tile, t / GROUP,
                                       __ATOMIC_RELEASE, __HIP_MEMORY_SCOPE_AGENT);
            } else {
                light_barrier();   // LDS visibility only; vmem stays in flight
                // deferred slab store of h(t-1): full step before next drain
                _Float16* slabP = slab + (size_t)((t - 1) * 16 + tile) * 2048;
                #pragma unroll
                for (int i = 0; i < 4; ++i)
                    slabP[(quad * 4 + i) * 128 + j0] = hh[i];
            }

            half8 ah[4];
            #pragma unroll
            for (int kt = 0; kt < 4; ++kt)
                ah[kt] = *(const half8*)(hdb + pbo + hoff[kt]);

            // recurrent MFMAs into accI (which already holds bias + x(t)-part)
            #pragma unroll
            for (int kt = 0; kt < 4; ++kt)
                #pragma unroll
                for (int nt = 0; nt < 4; ++nt) {
                    half8 bfr = *(const half8*)(wrec + nt * 16384 + j0 * 128 + swz[kt]);
                    accI[nt] = __builtin_amdgcn_mfma_f32_16x16x32_f16(ah[kt], bfr, accI[nt], 0, 0, 0);
                }

            // prefetch x(t+2)
            half8 fx0, fx1;
            f32x4 ff0, ff1, ff2, ff3;
            {
                int tn2 = (t + 2 < T_STEPS) ? t + 2 : T_STEPS - 1;
                if constexpr (XH) {
                    const _Float16* xq = xph + (size_t)tn2 * (BATCH * DIN);
                    fx0 = *(const half8*)(xq);
                    fx1 = *(const half8*)(xq + 32);
                } else {
                    const float* xq = xpf + (size_t)tn2 * (BATCH * DIN);
                    ff0 = *(const f32x4*)(xq);      ff1 = *(const f32x4*)(xq + 4);
                    ff2 = *(const f32x4*)(xq + 32); ff3 = *(const f32x4*)(xq + 36);
                }
            }

            // tail: accN(t+1) = bias + x(t+1)-part (buffer fetched last step;
            // MFMA pipe overlaps the activation VALU block below)
            f32x4 accN[4];
            {
                half8 c0, c1;
                if constexpr (XH) { c0 = bx0; c1 = bx1; }
                else {
                    #pragma unroll
                    for (int jj = 0; jj < 4; ++jj) {
                        c0[jj] = (_Float16)bf0[jj]; c0[jj+4] = (_Float16)bf1[jj];
                        c1[jj] = (_Float16)bf2[jj]; c1[jj+4] = (_Float16)bf3[jj];
                    }
                }
                #pragma unroll
                for (int nt = 0; nt < 4; ++nt) {
                    f32x4 b = {bias[nt], bias[nt], bias[nt], bias[nt]};
                    accN[nt] = b;
                }
                #pragma unroll
                for (int nt = 0; nt < 4; ++nt)
                    accN[nt] = __builtin_amdgcn_mfma_f32_16x16x32_f16(c0, wresf[nt][0], accN[nt], 0, 0, 0);
                #pragma unroll
                for (int nt = 0; nt < 4; ++nt)
                    accN[nt] = __builtin_amdgcn_mfma_f32_16x16x32_f16(c1, wresf[nt][1], accN[nt], 0, 0, 0);
            }

            _Float16* slabT = slab + (size_t)(t * 16 + tile) * 2048;
            #pragma unroll
            for (int i = 0; i < 4; ++i) {
                float ig = sig2(accI[0][i]);
                float fg = sig2(accI[1][i]);
                float gg = tanh2(accI[2][i]);
                float og = sig2(accI[3][i]);
                float c  = fg * cc[i] + ig * gg;
                cc[i] = c;
                _Float16 hf = (_Float16)(og * tanh_c(c));
                hdb[cbo + w0off[i]] = hf;                       // swizzled, recurrence
                if (lt == GROUP - 1)
                    slabT[(quad * 4 + i) * 128 + j0] = hf;      // group end: store now
                else
                    hh[i] = hf;                                 // defer to next step
            }

            // rotate pipeline state
            #pragma unroll
            for (int nt = 0; nt < 4; ++nt) accI[nt] = accN[nt];
            if constexpr (XH) { bx0 = fx0; bx1 = fx1; }
            else { bf0 = ff0; bf1 = ff1; bf2 = ff2; bf3 = ff3; }
        }
        __syncthreads();   // drain group-end stores of h(T-1)
        if (tid == 0)
            __hip_atomic_store(flags + (NGRP - 1) * 16 + tile, NGRP,
                               __ATOMIC_RELEASE, __HIP_MEMORY_SCOPE_AGENT);
    } else {
        // ================= layer-1 consumer + head =================
        if (tid == 0) {   // wait for group 0
            while (__hip_atomic_load(flags + tile, __ATOMIC_ACQUIRE,
                                     __HIP_MEMORY_SCOPE_AGENT) < 1)
                __builtin_amdgcn_s_sleep(1);
            asm volatile("s_waitcnt vmcnt(0)" ::: "memory");   // inv complete
        }
        __syncthreads();   // order acquire before all waves' slab loads

        // pre-loop: accI(0) = bias + h0(0)-part; buffer h0(1)
        half8 uA[4];       // holds h0(t+1) for the tail accN
        f32x4 accI[4];
        {
            const _Float16* s0 = slab + (size_t)tile * 2048;
            half8 cA[4];
            #pragma unroll
            for (int kt = 0; kt < 4; ++kt)
                cA[kt] = *(const half8*)(s0 + col * 128 + kt * 32 + quad * 8);
            #pragma unroll
            for (int nt = 0; nt < 4; ++nt) {
                f32x4 b = {bias[nt], bias[nt], bias[nt], bias[nt]};
                accI[nt] = b;
            }
            #pragma unroll
            for (int kt = 0; kt < 4; ++kt)
                #pragma unroll
                for (int nt = 0; nt < 4; ++nt)
                    accI[nt] = __builtin_amdgcn_mfma_f32_16x16x32_f16(cA[kt], wresf[nt][kt], accI[nt], 0, 0, 0);
            const _Float16* s1 = slab + (size_t)(16 + tile) * 2048;   // slot 1 (group 0)
            #pragma unroll
            for (int kt = 0; kt < 4; ++kt)
                uA[kt] = *(const half8*)(s1 + col * 128 + kt * 32 + quad * 8);
        }

        #pragma unroll 2
        for (int t = 0; t < T_STEPS; ++t) {
            const int pbo = (t & 1) * 2048, cbo = pbo ^ 2048;
            const int lt = t & (GROUP - 1);
            if (lt == 0) __syncthreads();   // full: orders prior group's acquire
            else         light_barrier();   // LDS visibility only

            half8 a1[4];
            #pragma unroll
            for (int kt = 0; kt < 4; ++kt)
                a1[kt] = *(const half8*)(hdb + pbo + hoff[kt]);

            // recurrent MFMAs into accI (already holds bias + h0(t)-part)
            #pragma unroll
            for (int kt = 0; kt < 4; ++kt)
                #pragma unroll
                for (int nt = 0; nt < 4; ++nt) {
                    half8 bfr = *(const half8*)(wrec + nt * 16384 + j0 * 128 + swz[kt]);
                    accI[nt] = __builtin_amdgcn_mfma_f32_16x16x32_f16(a1[kt], bfr, accI[nt], 0, 0, 0);
                }

            // poll NEXT group's flag mid-group; barriers at t+1/t+2 order it
            // for the cross-boundary prefetches
            if (lt == 12 && tid == 0) {
                int g1 = (t >> 4) + 1;
                if (g1 < NGRP) {
                    while (__hip_atomic_load(flags + g1 * 16 + tile, __ATOMIC_ACQUIRE,
                                             __HIP_MEMORY_SCOPE_AGENT) < g1 + 1)
                        __builtin_amdgcn_s_sleep(1);
                    asm volatile("s_waitcnt vmcnt(0)" ::: "memory");   // inv complete
                }
            }

            // prefetch slab slot t+2 (flag for its group already confirmed)
            half8 fA[4];
            {
                int tn2 = (t + 2 < T_STEPS) ? t + 2 : T_STEPS - 1;
                const _Float16* sq = slab + (size_t)(tn2 * 16 + tile) * 2048;
                #pragma unroll
                for (int kt = 0; kt < 4; ++kt)
                    fA[kt] = *(const half8*)(sq + col * 128 + kt * 32 + quad * 8);
            }

            // tail: accN(t+1) = bias + h0(t+1)-part (uA fetched last step;
            // MFMA pipe overlaps the activation VALU block below)
            f32x4 accN[4];
            #pragma unroll
            for (int nt = 0; nt < 4; ++nt) {
                f32x4 b = {bias[nt], bias[nt], bias[nt], bias[nt]};
                accN[nt] = b;
            }
            #pragma unroll
            for (int kt = 0; kt < 4; ++kt)
                #pragma unroll
                for (int nt = 0; nt < 4; ++nt)
                    accN[nt] = __builtin_amdgcn_mfma_f32_16x16x32_f16(uA[kt], wresf[nt][kt], accN[nt], 0, 0, 0);

            #pragma unroll
            for (int i = 0; i < 4; ++i) {
                float ig = sig2(accI[0][i]);
                float fg = sig2(accI[1][i]);
                float gg = tanh2(accI[2][i]);
                float og = sig2(accI[3][i]);
                float c  = fg * cc[i] + ig * gg;
                cc[i] = c;
                hdb[cbo + w0off[i]] = (_Float16)(og * tanh_c(c));
            }

            // value head for step t-1 on wave 7 (reads pbo buffer = h1(t-1))
            if (w == 7) {
                f32x4 vh = {0.f, 0.f, 0.f, 0.f};
                #pragma unroll
                for (int kt = 0; kt < 4; ++kt) {
                    half8 av = *(const half8*)(hdb + pbo + hoff[kt]);
                    half8 bw = *(const half8*)(woutl + kt * 32 + quad * 8);
                    if (col != 0) {
                        #pragma unroll
                        for (int jj = 0; jj < 8; ++jj) bw[jj] = (_Float16)0.0f;
                    }
                    vh = __builtin_amdgcn_mfma_f32_16x16x32_f16(av, bw, vh, 0, 0, 0);
                }
                if (t > 0 && col == 0) {
                    f32x4 vo = {vh[0] + bout, vh[1] + bout, vh[2] + bout, vh[3] + bout};
                    *(f32x4*)(out + (size_t)(t - 1) * BATCH + rowbase + quad * 4) = vo;
                }
            }

            // rotate pipeline state
            #pragma unroll
            for (int nt = 0; nt < 4; ++nt) accI[nt] = accN[nt];
            #pragma unroll
            for (int kt = 0; kt < 4; ++kt) uA[kt] = fA[kt];
        }
        __syncthreads();
        if (w == 7) {   // head for t = T-1
            const int fbo = (((T_STEPS - 1) & 1) ^ 1) * 2048;
            f32x4 vh = {0.f, 0.f, 0.f, 0.f};
            #pragma unroll
            for (int kt = 0; kt < 4; ++kt) {
                half8 av = *(const half8*)(hdb + fbo + hoff[kt]);
                half8 bw = *(const half8*)(woutl + kt * 32 + quad * 8);
                if (col != 0) {
                    #pragma unroll
                    for (int jj = 0; jj < 8; ++jj) bw[jj] = (_Float16)0.0f;
                }
                vh = __builtin_amdgcn_mfma_f32_16x16x32_f16(av, bw, vh, 0, 0, 0);
            }
            if (col == 0) {
                f32x4 vo = {vh[0] + bout, vh[1] + bout, vh[2] + bout, vh[3] + bout};
                *(f32x4*)(out + (size_t)(T_STEPS - 1) * BATCH + rowbase + quad * 4) = vo;
            }
        }
    }
}

// =====================  monolithic fallback (R2 structure, scaled act)  =====
#define MONO_LDS_BYTES ((73728 + 128) * 2)

template<bool XH>
__global__ __launch_bounds__(512, 2) void lstm_mono(
        const float* __restrict__ state32, const _Float16* __restrict__ wsw,
        const float* __restrict__ b_ih0, const float* __restrict__ b_hh0,
        const float* __restrict__ b_ih1, const float* __restrict__ b_hh1,
        const float* __restrict__ w_out, const float* __restrict__ b_out,
        float* __restrict__ out) {
    extern __shared__ _Float16 lds[];
    _Float16* whh1  = lds;
    _Float16* h0b   = lds + 65536;
    _Float16* h1b   = lds + 69632;
    _Float16* woutl = lds + 73728;

    const int tid  = threadIdx.x;
    const int w    = tid >> 6;
    const int lane = tid & 63;
    const int col  = lane & 15;
    const int quad = lane >> 4;
    const int rowbase = blockIdx.x * 16;
    const int j0 = w * 16 + col;

    const _Float16* whh1g = wsw + WH_HH1;
    #pragma unroll
    for (int it = 0; it < 16; ++it) {
        int flat = (it * 512 + tid) * 8;
        int r = flat >> 7, chunk = (flat >> 3) & 15;
        *(half8*)(whh1 + r * 128 + ((chunk ^ (r & 15)) * 8)) = *(const half8*)(whh1g + flat);
    }
    {
        half8 z;
        #pragma unroll
        for (int jj = 0; jj < 8; ++jj) z[jj] = (_Float16)0.0f;
        for (int i = tid * 8; i < 8192; i += 4096) *(half8*)(h0b + i) = z;
    }
    if (tid < 128) woutl[tid] = (_Float16)w_out[tid];

    half8 whh0f[4][4], wih1f[4][4];
    float bias0[4], bias1[4];
    #pragma unroll
    for (int nt = 0; nt < 4; ++nt) {
        int j = nt * 128 + j0;
        float sc = (nt == 2) ? LOG2E2 : LOG2E;
        #pragma unroll
        for (int kt = 0; kt < 4; ++kt) {
            whh0f[nt][kt] = *(const half8*)(wsw + WH_HH0 + j * 128 + kt * 32 + quad * 8);
            wih1f[nt][kt] = *(const half8*)(wsw + WH_IH1 + j * 128 + kt * 32 + quad * 8);
        }
        bias0[nt] = (b_ih0[j] + b_hh0[j]) * sc;
        bias1[nt] = (b_ih1[j] + b_hh1[j]) * sc;
    }
    const float bout = b_out[0];

    int swz[4], hoff[4], w0off[4];
    #pragma unroll
    for (int kt = 0; kt < 4; ++kt) {
        swz[kt]  = ((kt * 4 + quad) ^ col) * 8;
        hoff[kt] = col * 128 + swz[kt];
    }
    #pragma unroll
    for (int i = 0; i < 4; ++i) {
        int row = quad * 4 + i;
        w0off[i] = row * 128 + (((2 * w + (col >> 3)) ^ row) * 8) + (col & 7);
    }
    float c0[4] = {0.f,0.f,0.f,0.f}, c1[4] = {0.f,0.f,0.f,0.f};

    const _Float16* xph = wsw + WH_X2 + (size_t)(rowbase + col) * DIN + quad * 8;
    const float*    xpf = state32 + (size_t)(rowbase + col) * DIN + quad * 8;
    half8 nxh0, nxh1;
    f32x4 nxf0, nxf1, nxf2, nxf3;
    if constexpr (XH) {
        nxh0 = *(const half8*)(xph); nxh1 = *(const half8*)(xph + 32);
    } else {
        nxf0 = *(const f32x4*)(xpf);      nxf1 = *(const f32x4*)(xpf + 4);
        nxf2 = *(const f32x4*)(xpf + 32); nxf3 = *(const f32x4*)(xpf + 36);
    }
    __syncthreads();
    const _Float16* wih0g = wsw + WH_IH0;

    #pragma unroll 1
    for (int t = 0; t < T_STEPS; ++t) {
        const int pbo = (t & 1) * 2048, cbo = pbo ^ 2048;
        half8 ax0, ax1;
        if constexpr (XH) { ax0 = nxh0; ax1 = nxh1; }
        else {
            #pragma unroll
            for (int jj = 0; jj < 4; ++jj) {
                ax0[jj]   = (_Float16)nxf0[jj]; ax0[jj+4] = (_Float16)nxf1[jj];
                ax1[jj]   = (_Float16)nxf2[jj]; ax1[jj+4] = (_Float16)nxf3[jj];
            }
        }
        half8 wif[4][2];
        #pragma unroll
        for (int nt = 0; nt < 4; ++nt)
            #pragma unroll
            for (int kt = 0; kt < 2; ++kt)
                wif[nt][kt] = *(const half8*)(wih0g + (nt * 128 + j0) * 64 + kt * 32 + quad * 8);
        half8 ah[4];
        #pragma unroll
        for (int kt = 0; kt < 4; ++kt)
            ah[kt] = *(const half8*)(h0b + pbo + hoff[kt]);

        f32x4 acc[4];
        #pragma unroll
        for (int nt = 0; nt < 4; ++nt) {
            f32x4 b = {bias0[nt], bias0[nt], bias0[nt], bias0[nt]};
            acc[nt] = b;
        }
        #pragma unroll
        for (int kt = 0; kt < 4; ++kt)
            #pragma unroll
            for (int nt = 0; nt < 4; ++nt)
                acc[nt] = __builtin_amdgcn_mfma_f32_16x16x32_f16(ah[kt], whh0f[nt][kt], acc[nt], 0, 0, 0);
        #pragma unroll
        for (int kt = 0; kt < 2; ++kt) {
            half8 axk = kt ? ax1 : ax0;
            #pragma unroll
            for (int nt = 0; nt < 4; ++nt)
                acc[nt] = __builtin_amdgcn_mfma_f32_16x16x32_f16(axk, wif[nt][kt], acc[nt], 0, 0, 0);
        }
        {
            int tn = (t + 1 < T_STEPS) ? t + 1 : t;
            if constexpr (XH) {
                const _Float16* xq = xph + (size_t)tn * (BATCH * DIN);
                nxh0 = *(const half8*)(xq); nxh1 = *(const half8*)(xq + 32);
            } else {
                const float* xq = xpf + (size_t)tn * (BATCH * DIN);
                nxf0 = *(const f32x4*)(xq);      nxf1 = *(const f32x4*)(xq + 4);
                nxf2 = *(const f32x4*)(xq + 32); nxf3 = *(const f32x4*)(xq + 36);
            }
        }
        #pragma unroll
        for (int i = 0; i < 4; ++i) {
            float ig = sig2(acc[0][i]);
            float fg = sig2(acc[1][i]);
            float gg = tanh2(acc[2][i]);
            float og = sig2(acc[3][i]);
            float c  = fg * c0[i] + ig * gg;
            c0[i] = c;
            h0b[cbo + w0off[i]] = (_Float16)(og * tanh_c(c));
        }
        __syncthreads();

        #pragma unroll
        for (int nt = 0; nt < 4; ++nt) {
            f32x4 b = {bias1[nt], bias1[nt], bias1[nt], bias1[nt]};
            acc[nt] = b;
        }
        #pragma unroll
        for (int kt = 0; kt < 4; ++kt) {
            half8 a0 = *(const half8*)(h0b + cbo + hoff[kt]);
            half8 a1 = *(const half8*)(h1b + pbo + hoff[kt]);
            #pragma unroll
            for (int nt = 0; nt < 4; ++nt)
                acc[nt] = __builtin_amdgcn_mfma_f32_16x16x32_f16(a0, wih1f[nt][kt], acc[nt], 0, 0, 0);
            #pragma unroll
            for (int nt = 0; nt < 4; ++nt) {
                half8 bfr = *(const half8*)(whh1 + nt * 16384 + j0 * 128 + swz[kt]);
                acc[nt] = __builtin_amdgcn_mfma_f32_16x16x32_f16(a1, bfr, acc[nt], 0, 0, 0);
            }
        }
        #pragma unroll
        for (int i = 0; i < 4; ++i) {
            float ig = sig2(acc[0][i]);
            float fg = sig2(acc[1][i]);
            float gg = tanh2(acc[2][i]);
            float og = sig2(acc[3][i]);
            float c  = fg * c1[i] + ig * gg;
            c1[i] = c;
            h1b[cbo + w0off[i]] = (_Float16)(og * tanh_c(c));
        }
        if (w == 7) {
            f32x4 vh = {0.f, 0.f, 0.f, 0.f};
            #pragma unroll
            for (int kt = 0; kt < 4; ++kt) {
                half8 a1 = *(const half8*)(h1b + pbo + hoff[kt]);
                half8 bw = *(const half8*)(woutl + kt * 32 + quad * 8);
                if (col != 0) {
                    #pragma unroll
                    for (int jj = 0; jj < 8; ++jj) bw[jj] = (_Float16)0.0f;
                }
                vh = __builtin_amdgcn_mfma_f32_16x16x32_f16(a1, bw, vh, 0, 0, 0);
            }
            if (t > 0 && col == 0) {
                f32x4 vo = {vh[0] + bout, vh[1] + bout, vh[2] + bout, vh[3] + bout};
                *(f32x4*)(out + (size_t)(t - 1) * BATCH + rowbase + quad * 4) = vo;
            }
        }
    }
    __syncthreads();
    if (w == 7) {
        const int fbo = (((T_STEPS - 1) & 1) ^ 1) * 2048;
        f32x4 vh = {0.f, 0.f, 0.f, 0.f};
        #pragma unroll
        for (int kt = 0; kt < 4; ++kt) {
            half8 a1 = *(const half8*)(h1b + fbo + hoff[kt]);
            half8 bw = *(const half8*)(woutl + kt * 32 + quad * 8);
            if (col != 0) {
                #pragma unroll
                for (int jj = 0; jj < 8; ++jj) bw[jj] = (_Float16)0.0f;
            }
            vh = __builtin_amdgcn_mfma_f32_16x16x32_f16(a1, bw, vh, 0, 0, 0);
        }
        if (col == 0) {
            f32x4 vo = {vh[0] + bout, vh[1] + bout, vh[2] + bout, vh[3] + bout};
            *(f32x4*)(out + (size_t)(T_STEPS - 1) * BATCH + rowbase + quad * 4) = vo;
        }
    }
}

extern "C" void kernel_launch(void* const* d_in, const int* in_sizes, int n_in,
                              void* d_out, int out_size, void* d_ws, size_t ws_size,
                              hipStream_t stream) {
    const float* state = (const float*)d_in[0];
    const float* wih0  = (const float*)d_in[1];
    const float* whh0  = (const float*)d_in[2];
    const float* bih0  = (const float*)d_in[3];
    const float* bhh0  = (const float*)d_in[4];
    const float* wih1  = (const float*)d_in[5];
    const float* whh1  = (const float*)d_in[6];
    const float* bih1  = (const float*)d_in[7];
    const float* bhh1  = (const float*)d_in[8];
    const float* wout  = (const float*)d_in[9];
    const float* bout  = (const float*)d_in[10];
    _Float16* wsh = (_Float16*)d_ws;
    float* outp = (float*)d_out;

    prep_weights<<<896, 256, 0, stream>>>(wih0, whh0, wih1, whh1, wsh);

    if (ws_size >= WS2_TOTAL) {
        prep_state<<<4096, 256, 0, stream>>>(state, wsh + WH_X2);
        lstm_pipe<true><<<32, 512, PIPE_LDS_BYTES, stream>>>(
            state, wsh, bih0, bhh0, bih1, bhh1, wout, bout,
            wsh + WH_SLAB2, (int*)((char*)d_ws + WB_FLAG2), wsh + WH_X2, outp);
    } else if (ws_size >= WS1_TOTAL) {
        lstm_pipe<false><<<32, 512, PIPE_LDS_BYTES, stream>>>(
            state, wsh, bih0, bhh0, bih1, bhh1, wout, bout,
            wsh + WH_SLAB1, (int*)((char*)d_ws + WB_FLAG1), nullptr, outp);
    } else if (ws_size >= WS0XH_TOTAL) {
        prep_state<<<4096, 256, 0, stream>>>(state, wsh + WH_X2);
        lstm_mono<true><<<16, 512, MONO_LDS_BYTES, stream>>>(
            state, wsh, bih0, bhh0, bih1, bhh1, wout, bout, outp);
    } else {
        lstm_mono<false><<<16, 512, MONO_LDS_BYTES, stream>>>(
            state, wsh, bih0, bhh0, bih1, bhh1, wout, bout, outp);
    }
}

// Round 13
// 625.637 us; speedup vs baseline: 1.1327x; 1.1327x over previous
//
#include <hip/hip_runtime.h>

// LSTM_Critic: T=512, B=256, D_IN=64, H=128. Round-13 = R11 (best: 606us; R12
// light barriers regressed and are reverted) + ONE change: the 16 recurrent
// weight B-frags are hoisted OUT of the T-loop into plain registers (wpf).
// Rationale: ds_read_b128 = 1KB/wave -> R11 streams 160KB/CU/step through the
// shared LDS pipe (~1280-1880 cyc at 85-128 B/cyc) -- the dominant per-step
// wall. The frags are loop-invariant; an unpinned hoist forces residency by C
// semantics (hdb stores may alias wrec, so no re-load), and gfx950 MFMA reads
// B from VGPR or AGPR natively (no copies -- R6's "+a" pinning, not AGPR
// itself, caused the copy storm). Post-barrier LDS drops to 32KB/CU/step.

#define T_STEPS 512
#define BATCH   256
#define DIN     64
#define GROUP   16
#define NGRP    (T_STEPS / GROUP)

typedef _Float16 half8 __attribute__((ext_vector_type(8)));
typedef float    f32x4 __attribute__((ext_vector_type(4)));

#define LOG2E  1.44269504088896f
#define LOG2E2 2.88539008177793f

// ---- ws layout (fp16 element offsets unless noted) ----
#define WH_IH0 0          // [512][64]
#define WH_HH0 32768      // [512][128]
#define WH_IH1 98304      // [512][128]
#define WH_HH1 163840     // [512][128]
// mode 2: + fp16 x + slab + flags
#define WH_X2     229376                   // 8388608 halfs
#define WH_SLAB2  8617984                  // 16777216 halfs (512*16*2048)
#define WB_FLAG2  50790400                 // byte offset, 8192 ints reserved
#define WS2_TOTAL 50823168
// mode 1: + slab + flags (x stays fp32 from input)
#define WH_SLAB1  229376
#define WB_FLAG1  34013184
#define WS1_TOTAL 34045952
// mode 0 (monolithic): optional fp16 x at WH_X2
#define WS0XH_TOTAL ((size_t)(WH_X2 + 8388608) * 2)

__global__ void prep_weights(const float* __restrict__ wih0,
                             const float* __restrict__ whh0,
                             const float* __restrict__ wih1,
                             const float* __restrict__ whh1,
                             _Float16* __restrict__ ws) {
    int idx = blockIdx.x * 256 + threadIdx.x;   // 229376 total
    float v; int row;
    if (idx < 32768)       { row = idx >> 6;             v = wih0[idx]; }
    else if (idx < 98304)  { row = (idx - 32768) >> 7;   v = whh0[idx - 32768]; }
    else if (idx < 163840) { row = (idx - 98304) >> 7;   v = wih1[idx - 98304]; }
    else                   { row = (idx - 163840) >> 7;  v = whh1[idx - 163840]; }
    // gate chunk 2 (g) uses tanh -> scale 2*log2e; others sigmoid -> log2e
    float sc = ((row >> 7) == 2) ? LOG2E2 : LOG2E;
    ws[idx] = (_Float16)(v * sc);
}

__global__ void prep_state(const float* __restrict__ s, _Float16* __restrict__ d) {
    int i = (blockIdx.x * 256 + threadIdx.x) * 8;   // 8388608 elements
    f32x4 a = *(const f32x4*)(s + i);
    f32x4 b = *(const f32x4*)(s + i + 4);
    half8 h;
    h[0]=(_Float16)a[0]; h[1]=(_Float16)a[1]; h[2]=(_Float16)a[2]; h[3]=(_Float16)a[3];
    h[4]=(_Float16)b[0]; h[5]=(_Float16)b[1]; h[6]=(_Float16)b[2]; h[7]=(_Float16)b[3];
    *(half8*)(d + i) = h;
}

// activations on pre-scaled gate values
__device__ __forceinline__ float sig2(float y) {        // y = x*log2e
    return __builtin_amdgcn_rcpf(1.0f + __builtin_amdgcn_exp2f(-y));
}
__device__ __forceinline__ float tanh2(float y2) {      // y2 = x*2*log2e
    return 1.0f - 2.0f * __builtin_amdgcn_rcpf(1.0f + __builtin_amdgcn_exp2f(y2));
}
__device__ __forceinline__ float tanh_c(float c) {      // c unscaled
    return 1.0f - 2.0f * __builtin_amdgcn_rcpf(1.0f + __builtin_amdgcn_exp2f(c * LOG2E2));
}

// =====================  pipelined kernel  =====================
// LDS (halfs): wrec[512][128] swizzled = 65536 | hdb[2][16][128] = 4096 | woutl[128]
#define PIPE_LDS_BYTES ((65536 + 4096 + 128) * 2)

template<bool XH>
__global__ __launch_bounds__(512, 1) void lstm_pipe(
        const float* __restrict__ state32, const _Float16* __restrict__ wsw,
        const float* __restrict__ b_ih0, const float* __restrict__ b_hh0,
        const float* __restrict__ b_ih1, const float* __restrict__ b_hh1,
        const float* __restrict__ w_out, const float* __restrict__ b_out,
        _Float16* __restrict__ slab, int* __restrict__ flags,
        const _Float16* __restrict__ xh, float* __restrict__ out) {
    extern __shared__ _Float16 lds[];
    _Float16* wrec  = lds;            // recurrent weights (whh0 / whh1), swizzled
    _Float16* hdb   = lds + 65536;    // h double-buffer [2][16][128], swizzled
    _Float16* woutl = lds + 69632;    // head weights (consumer)

    const int tid  = threadIdx.x;
    const int w    = tid >> 6;
    const int lane = tid & 63;
    const int col  = lane & 15;
    const int quad = lane >> 4;
    const bool producer = blockIdx.x < 16;
    const int tile = blockIdx.x & 15;
    const int rowbase = tile * 16;
    const int j0 = w * 16 + col;

    // ---- one-time LDS init ----
    const _Float16* wrg = wsw + (producer ? WH_HH0 : WH_HH1);
    #pragma unroll
    for (int it = 0; it < 16; ++it) {
        int flat = (it * 512 + tid) * 8;
        int r = flat >> 7, chunk = (flat >> 3) & 15;
        *(half8*)(wrec + r * 128 + ((chunk ^ (r & 15)) * 8)) = *(const half8*)(wrg + flat);
    }
    {
        half8 z;
        #pragma unroll
        for (int jj = 0; jj < 8; ++jj) z[jj] = (_Float16)0.0f;
        *(half8*)(hdb + tid * 8) = z;   // 512*8 = 4096 halfs
    }
    if (!producer && tid < 128) woutl[tid] = (_Float16)w_out[tid];

    // ---- resident input-side B-frags + scaled biases ----
    half8 wresf[4][4];   // producer uses [nt][0..1] (wih0), consumer [nt][0..3] (wih1)
    float bias[4];
    #pragma unroll
    for (int nt = 0; nt < 4; ++nt) {
        int j = nt * 128 + j0;
        float sc = (nt == 2) ? LOG2E2 : LOG2E;
        if (producer) {
            #pragma unroll
            for (int kt = 0; kt < 2; ++kt)
                wresf[nt][kt] = *(const half8*)(wsw + WH_IH0 + j * 64 + kt * 32 + quad * 8);
            bias[nt] = (b_ih0[j] + b_hh0[j]) * sc;
        } else {
            #pragma unroll
            for (int kt = 0; kt < 4; ++kt)
                wresf[nt][kt] = *(const half8*)(wsw + WH_IH1 + j * 128 + kt * 32 + quad * 8);
            bias[nt] = (b_ih1[j] + b_hh1[j]) * sc;
        }
    }
    const float bout = b_out[0];

    // swizzled-address precompute (R2-verified, 0 bank conflicts)
    int swz[4], hoff[4], w0off[4];
    #pragma unroll
    for (int kt = 0; kt < 4; ++kt) {
        swz[kt]  = ((kt * 4 + quad) ^ col) * 8;
        hoff[kt] = col * 128 + swz[kt];
    }
    #pragma unroll
    for (int i = 0; i < 4; ++i) {
        int row = quad * 4 + i;
        w0off[i] = row * 128 + (((2 * w + (col >> 3)) ^ row) * 8) + (col & 7);
    }
    float cc[4] = {0.f, 0.f, 0.f, 0.f};

    __syncthreads();

    // ---- loop-invariant recurrent B-frags: hoisted to registers ONCE ----
    // (unpinned; values must stay live across the loop since hdb stores may
    //  alias wrec -- the compiler cannot legally re-load them)
    half8 wpf[4][4];
    #pragma unroll
    for (int kt = 0; kt < 4; ++kt)
        #pragma unroll
        for (int nt = 0; nt < 4; ++nt)
            wpf[kt][nt] = *(const half8*)(wrec + nt * 16384 + j0 * 128 + swz[kt]);

    if (producer) {
        // ================= layer-0 producer =================
        const _Float16* xph = xh + (size_t)(rowbase + col) * DIN + quad * 8;
        const float*    xpf = state32 + (size_t)(rowbase + col) * DIN + quad * 8;

        // pre-loop: accI(0) = bias + x(0)-part; buffer x(1)
        half8 bx0, bx1;                      // XH buffer holding x(t+1)
        f32x4 bf0, bf1, bf2, bf3;            // non-XH buffer
        f32x4 accI[4];
        {
            half8 a0, a1v;
            if constexpr (XH) {
                a0  = *(const half8*)(xph);
                a1v = *(const half8*)(xph + 32);
            } else {
                f32x4 t0 = *(const f32x4*)(xpf),      t1 = *(const f32x4*)(xpf + 4);
                f32x4 t2 = *(const f32x4*)(xpf + 32), t3 = *(const f32x4*)(xpf + 36);
                #pragma unroll
                for (int jj = 0; jj < 4; ++jj) {
                    a0[jj]  = (_Float16)t0[jj]; a0[jj+4]  = (_Float16)t1[jj];
                    a1v[jj] = (_Float16)t2[jj]; a1v[jj+4] = (_Float16)t3[jj];
                }
            }
            #pragma unroll
            for (int nt = 0; nt < 4; ++nt) {
                f32x4 b = {bias[nt], bias[nt], bias[nt], bias[nt]};
                accI[nt] = b;
            }
            #pragma unroll
            for (int nt = 0; nt < 4; ++nt)
                accI[nt] = __builtin_amdgcn_mfma_f32_16x16x32_f16(a0, wresf[nt][0], accI[nt], 0, 0, 0);
            #pragma unroll
            for (int nt = 0; nt < 4; ++nt)
                accI[nt] = __builtin_amdgcn_mfma_f32_16x16x32_f16(a1v, wresf[nt][1], accI[nt], 0, 0, 0);
            // buffer x(1)
            if constexpr (XH) {
                bx0 = *(const half8*)(xph + BATCH * DIN);
                bx1 = *(const half8*)(xph + BATCH * DIN + 32);
            } else {
                bf0 = *(const f32x4*)(xpf + BATCH * DIN);
                bf1 = *(const f32x4*)(xpf + BATCH * DIN + 4);
                bf2 = *(const f32x4*)(xpf + BATCH * DIN + 32);
                bf3 = *(const f32x4*)(xpf + BATCH * DIN + 36);
            }
        }
        _Float16 hh[4];   // held h(t-1), stored at top of step t

        #pragma unroll 2
        for (int t = 0; t < T_STEPS; ++t) {
            const int pbo = (t & 1) * 2048, cbo = pbo ^ 2048;
            const int lt = t & (GROUP - 1);
            __syncthreads();   // t-1 LDS writes visible; vmcnt drained

            if (lt == 0) {
                // group (t/GROUP - 1) fully stored + drained -> publish
                if (t > 0 && tid == 0)
                    __hip_atomic_store(flags + (t / GROUP - 1) * 16 + tile, t / GROUP,
                                       __ATOMIC_RELEASE, __HIP_MEMORY_SCOPE_AGENT);
            } else {
                // deferred slab store of h(t-1): full step before next drain
                _Float16* slabP = slab + (size_t)((t - 1) * 16 + tile) * 2048;
                #pragma unroll
                for (int i = 0; i < 4; ++i)
                    slabP[(quad * 4 + i) * 128 + j0] = hh[i];
            }

            half8 ah[4];
            #pragma unroll
            for (int kt = 0; kt < 4; ++kt)
                ah[kt] = *(const half8*)(hdb + pbo + hoff[kt]);

            // recurrent MFMAs into accI (which already holds bias + x(t)-part)
            #pragma unroll
            for (int kt = 0; kt < 4; ++kt)
                #pragma unroll
                for (int nt = 0; nt < 4; ++nt)
                    accI[nt] = __builtin_amdgcn_mfma_f32_16x16x32_f16(ah[kt], wpf[kt][nt], accI[nt], 0, 0, 0);

            // prefetch x(t+2)
            half8 fx0, fx1;
            f32x4 ff0, ff1, ff2, ff3;
            {
                int tn2 = (t + 2 < T_STEPS) ? t + 2 : T_STEPS - 1;
                if constexpr (XH) {
                    const _Float16* xq = xph + (size_t)tn2 * (BATCH * DIN);
                    fx0 = *(const half8*)(xq);
                    fx1 = *(const half8*)(xq + 32);
                } else {
                    const float* xq = xpf + (size_t)tn2 * (BATCH * DIN);
                    ff0 = *(const f32x4*)(xq);      ff1 = *(const f32x4*)(xq + 4);
                    ff2 = *(const f32x4*)(xq + 32); ff3 = *(const f32x4*)(xq + 36);
                }
            }

            // tail: accN(t+1) = bias + x(t+1)-part (buffer fetched last step;
            // MFMA pipe overlaps the activation VALU block below)
            f32x4 accN[4];
            {
                half8 c0, c1;
                if constexpr (XH) { c0 = bx0; c1 = bx1; }
                else {
                    #pragma unroll
                    for (int jj = 0; jj < 4; ++jj) {
                        c0[jj] = (_Float16)bf0[jj]; c0[jj+4] = (_Float16)bf1[jj];
                        c1[jj] = (_Float16)bf2[jj]; c1[jj+4] = (_Float16)bf3[jj];
                    }
                }
                #pragma unroll
                for (int nt = 0; nt < 4; ++nt) {
                    f32x4 b = {bias[nt], bias[nt], bias[nt], bias[nt]};
                    accN[nt] = b;
                }
                #pragma unroll
                for (int nt = 0; nt < 4; ++nt)
                    accN[nt] = __builtin_amdgcn_mfma_f32_16x16x32_f16(c0, wresf[nt][0], accN[nt], 0, 0, 0);
                #pragma unroll
                for (int nt = 0; nt < 4; ++nt)
                    accN[nt] = __builtin_amdgcn_mfma_f32_16x16x32_f16(c1, wresf[nt][1], accN[nt], 0, 0, 0);
            }

            _Float16* slabT = slab + (size_t)(t * 16 + tile) * 2048;
            #pragma unroll
            for (int i = 0; i < 4; ++i) {
                float ig = sig2(accI[0][i]);
                float fg = sig2(accI[1][i]);
                float gg = tanh2(accI[2][i]);
                float og = sig2(accI[3][i]);
                float c  = fg * cc[i] + ig * gg;
                cc[i] = c;
                _Float16 hf = (_Float16)(og * tanh_c(c));
                hdb[cbo + w0off[i]] = hf;                       // swizzled, recurrence
                if (lt == GROUP - 1)
                    slabT[(quad * 4 + i) * 128 + j0] = hf;      // group end: store now
                else
                    hh[i] = hf;                                 // defer to next step
            }

            // rotate pipeline state
            #pragma unroll
            for (int nt = 0; nt < 4; ++nt) accI[nt] = accN[nt];
            if constexpr (XH) { bx0 = fx0; bx1 = fx1; }
            else { bf0 = ff0; bf1 = ff1; bf2 = ff2; bf3 = ff3; }
        }
        __syncthreads();   // drain group-end stores of h(T-1)
        if (tid == 0)
            __hip_atomic_store(flags + (NGRP - 1) * 16 + tile, NGRP,
                               __ATOMIC_RELEASE, __HIP_MEMORY_SCOPE_AGENT);
    } else {
        // ================= layer-1 consumer + head =================
        if (tid == 0) {   // wait for group 0
            while (__hip_atomic_load(flags + tile, __ATOMIC_ACQUIRE,
                                     __HIP_MEMORY_SCOPE_AGENT) < 1)
                __builtin_amdgcn_s_sleep(1);
        }
        __syncthreads();   // order acquire before all waves' slab loads

        // pre-loop: accI(0) = bias + h0(0)-part; buffer h0(1)
        half8 uA[4];       // holds h0(t+1) for the tail accN
        f32x4 accI[4];
        {
            const _Float16* s0 = slab + (size_t)tile * 2048;
            half8 cA[4];
            #pragma unroll
            for (int kt = 0; kt < 4; ++kt)
                cA[kt] = *(const half8*)(s0 + col * 128 + kt * 32 + quad * 8);
            #pragma unroll
            for (int nt = 0; nt < 4; ++nt) {
                f32x4 b = {bias[nt], bias[nt], bias[nt], bias[nt]};
                accI[nt] = b;
            }
            #pragma unroll
            for (int kt = 0; kt < 4; ++kt)
                #pragma unroll
                for (int nt = 0; nt < 4; ++nt)
                    accI[nt] = __builtin_amdgcn_mfma_f32_16x16x32_f16(cA[kt], wresf[nt][kt], accI[nt], 0, 0, 0);
            const _Float16* s1 = slab + (size_t)(16 + tile) * 2048;   // slot 1 (group 0)
            #pragma unroll
            for (int kt = 0; kt < 4; ++kt)
                uA[kt] = *(const half8*)(s1 + col * 128 + kt * 32 + quad * 8);
        }

        #pragma unroll 2
        for (int t = 0; t < T_STEPS; ++t) {
            const int pbo = (t & 1) * 2048, cbo = pbo ^ 2048;
            const int lt = t & (GROUP - 1);
            __syncthreads();   // t-1 LDS writes visible; orders any prior acquire

            half8 a1[4];
            #pragma unroll
            for (int kt = 0; kt < 4; ++kt)
                a1[kt] = *(const half8*)(hdb + pbo + hoff[kt]);

            // recurrent MFMAs into accI (already holds bias + h0(t)-part)
            #pragma unroll
            for (int kt = 0; kt < 4; ++kt)
                #pragma unroll
                for (int nt = 0; nt < 4; ++nt)
                    accI[nt] = __builtin_amdgcn_mfma_f32_16x16x32_f16(a1[kt], wpf[kt][nt], accI[nt], 0, 0, 0);

            // poll NEXT group's flag mid-group; barriers at t+1/t+2 order it
            // for the cross-boundary prefetches
            if (lt == 12 && tid == 0) {
                int g1 = (t >> 4) + 1;
                if (g1 < NGRP) {
                    while (__hip_atomic_load(flags + g1 * 16 + tile, __ATOMIC_ACQUIRE,
                                             __HIP_MEMORY_SCOPE_AGENT) < g1 + 1)
                        __builtin_amdgcn_s_sleep(1);
                }
            }

            // prefetch slab slot t+2 (flag for its group already confirmed)
            half8 fA[4];
            {
                int tn2 = (t + 2 < T_STEPS) ? t + 2 : T_STEPS - 1;
                const _Float16* sq = slab + (size_t)(tn2 * 16 + tile) * 2048;
                #pragma unroll
                for (int kt = 0; kt < 4; ++kt)
                    fA[kt] = *(const half8*)(sq + col * 128 + kt * 32 + quad * 8);
            }

            // tail: accN(t+1) = bias + h0(t+1)-part (uA fetched last step;
            // MFMA pipe overlaps the activation VALU block below)
            f32x4 accN[4];
            #pragma unroll
            for (int nt = 0; nt < 4; ++nt) {
                f32x4 b = {bias[nt], bias[nt], bias[nt], bias[nt]};
                accN[nt] = b;
            }
            #pragma unroll
            for (int kt = 0; kt < 4; ++kt)
                #pragma unroll
                for (int nt = 0; nt < 4; ++nt)
                    accN[nt] = __builtin_amdgcn_mfma_f32_16x16x32_f16(uA[kt], wresf[nt][kt], accN[nt], 0, 0, 0);

            #pragma unroll
            for (int i = 0; i < 4; ++i) {
                float ig = sig2(accI[0][i]);
                float fg = sig2(accI[1][i]);
                float gg = tanh2(accI[2][i]);
                float og = sig2(accI[3][i]);
                float c  = fg * cc[i] + ig * gg;
                cc[i] = c;
                hdb[cbo + w0off[i]] = (_Float16)(og * tanh_c(c));
            }

            // value head for step t-1 on wave 7 (reads pbo buffer = h1(t-1))
            if (w == 7) {
                f32x4 vh = {0.f, 0.f, 0.f, 0.f};
                #pragma unroll
                for (int kt = 0; kt < 4; ++kt) {
                    half8 av = *(const half8*)(hdb + pbo + hoff[kt]);
                    half8 bw = *(const half8*)(woutl + kt * 32 + quad * 8);
                    if (col != 0) {
                        #pragma unroll
                        for (int jj = 0; jj < 8; ++jj) bw[jj] = (_Float16)0.0f;
                    }
                    vh = __builtin_amdgcn_mfma_f32_16x16x32_f16(av, bw, vh, 0, 0, 0);
                }
                if (t > 0 && col == 0) {
                    f32x4 vo = {vh[0] + bout, vh[1] + bout, vh[2] + bout, vh[3] + bout};
                    *(f32x4*)(out + (size_t)(t - 1) * BATCH + rowbase + quad * 4) = vo;
                }
            }

            // rotate pipeline state
            #pragma unroll
            for (int nt = 0; nt < 4; ++nt) accI[nt] = accN[nt];
            #pragma unroll
            for (int kt = 0; kt < 4; ++kt) uA[kt] = fA[kt];
        }
        __syncthreads();
        if (w == 7) {   // head for t = T-1
            const int fbo = (((T_STEPS - 1) & 1) ^ 1) * 2048;
            f32x4 vh = {0.f, 0.f, 0.f, 0.f};
            #pragma unroll
            for (int kt = 0; kt < 4; ++kt) {
                half8 av = *(const half8*)(hdb + fbo + hoff[kt]);
                half8 bw = *(const half8*)(woutl + kt * 32 + quad * 8);
                if (col != 0) {
                    #pragma unroll
                    for (int jj = 0; jj < 8; ++jj) bw[jj] = (_Float16)0.0f;
                }
                vh = __builtin_amdgcn_mfma_f32_16x16x32_f16(av, bw, vh, 0, 0, 0);
            }
            if (col == 0) {
                f32x4 vo = {vh[0] + bout, vh[1] + bout, vh[2] + bout, vh[3] + bout};
                *(f32x4*)(out + (size_t)(T_STEPS - 1) * BATCH + rowbase + quad * 4) = vo;
            }
        }
    }
}

// =====================  monolithic fallback (R2 structure, scaled act)  =====
#define MONO_LDS_BYTES ((73728 + 128) * 2)

template<bool XH>
__global__ __launch_bounds__(512, 2) void lstm_mono(
        const float* __restrict__ state32, const _Float16* __restrict__ wsw,
        const float* __restrict__ b_ih0, const float* __restrict__ b_hh0,
        const float* __restrict__ b_ih1, const float* __restrict__ b_hh1,
        const float* __restrict__ w_out, const float* __restrict__ b_out,
        float* __restrict__ out) {
    extern __shared__ _Float16 lds[];
    _Float16* whh1  = lds;
    _Float16* h0b   = lds + 65536;
    _Float16* h1b   = lds + 69632;
    _Float16* woutl = lds + 73728;

    const int tid  = threadIdx.x;
    const int w    = tid >> 6;
    const int lane = tid & 63;
    const int col  = lane & 15;
    const int quad = lane >> 4;
    const int rowbase = blockIdx.x * 16;
    const int j0 = w * 16 + col;

    const _Float16* whh1g = wsw + WH_HH1;
    #pragma unroll
    for (int it = 0; it < 16; ++it) {
        int flat = (it * 512 + tid) * 8;
        int r = flat >> 7, chunk = (flat >> 3) & 15;
        *(half8*)(whh1 + r * 128 + ((chunk ^ (r & 15)) * 8)) = *(const half8*)(whh1g + flat);
    }
    {
        half8 z;
        #pragma unroll
        for (int jj = 0; jj < 8; ++jj) z[jj] = (_Float16)0.0f;
        for (int i = tid * 8; i < 8192; i += 4096) *(half8*)(h0b + i) = z;
    }
    if (tid < 128) woutl[tid] = (_Float16)w_out[tid];

    half8 whh0f[4][4], wih1f[4][4];
    float bias0[4], bias1[4];
    #pragma unroll
    for (int nt = 0; nt < 4; ++nt) {
        int j = nt * 128 + j0;
        float sc = (nt == 2) ? LOG2E2 : LOG2E;
        #pragma unroll
        for (int kt = 0; kt < 4; ++kt) {
            whh0f[nt][kt] = *(const half8*)(wsw + WH_HH0 + j * 128 + kt * 32 + quad * 8);
            wih1f[nt][kt] = *(const half8*)(wsw + WH_IH1 + j * 128 + kt * 32 + quad * 8);
        }
        bias0[nt] = (b_ih0[j] + b_hh0[j]) * sc;
        bias1[nt] = (b_ih1[j] + b_hh1[j]) * sc;
    }
    const float bout = b_out[0];

    int swz[4], hoff[4], w0off[4];
    #pragma unroll
    for (int kt = 0; kt < 4; ++kt) {
        swz[kt]  = ((kt * 4 + quad) ^ col) * 8;
        hoff[kt] = col * 128 + swz[kt];
    }
    #pragma unroll
    for (int i = 0; i < 4; ++i) {
        int row = quad * 4 + i;
        w0off[i] = row * 128 + (((2 * w + (col >> 3)) ^ row) * 8) + (col & 7);
    }
    float c0[4] = {0.f,0.f,0.f,0.f}, c1[4] = {0.f,0.f,0.f,0.f};

    const _Float16* xph = wsw + WH_X2 + (size_t)(rowbase + col) * DIN + quad * 8;
    const float*    xpf = state32 + (size_t)(rowbase + col) * DIN + quad * 8;
    half8 nxh0, nxh1;
    f32x4 nxf0, nxf1, nxf2, nxf3;
    if constexpr (XH) {
        nxh0 = *(const half8*)(xph); nxh1 = *(const half8*)(xph + 32);
    } else {
        nxf0 = *(const f32x4*)(xpf);      nxf1 = *(const f32x4*)(xpf + 4);
        nxf2 = *(const f32x4*)(xpf + 32); nxf3 = *(const f32x4*)(xpf + 36);
    }
    __syncthreads();
    const _Float16* wih0g = wsw + WH_IH0;

    #pragma unroll 1
    for (int t = 0; t < T_STEPS; ++t) {
        const int pbo = (t & 1) * 2048, cbo = pbo ^ 2048;
        half8 ax0, ax1;
        if constexpr (XH) { ax0 = nxh0; ax1 = nxh1; }
        else {
            #pragma unroll
            for (int jj = 0; jj < 4; ++jj) {
                ax0[jj]   = (_Float16)nxf0[jj]; ax0[jj+4] = (_Float16)nxf1[jj];
                ax1[jj]   = (_Float16)nxf2[jj]; ax1[jj+4] = (_Float16)nxf3[jj];
            }
        }
        half8 wif[4][2];
        #pragma unroll
        for (int nt = 0; nt < 4; ++nt)
            #pragma unroll
            for (int kt = 0; kt < 2; ++kt)
                wif[nt][kt] = *(const half8*)(wih0g + (nt * 128 + j0) * 64 + kt * 32 + quad * 8);
        half8 ah[4];
        #pragma unroll
        for (int kt = 0; kt < 4; ++kt)
            ah[kt] = *(const half8*)(h0b + pbo + hoff[kt]);

        f32x4 acc[4];
        #pragma unroll
        for (int nt = 0; nt < 4; ++nt) {
            f32x4 b = {bias0[nt], bias0[nt], bias0[nt], bias0[nt]};
            acc[nt] = b;
        }
        #pragma unroll
        for (int kt = 0; kt < 4; ++kt)
            #pragma unroll
            for (int nt = 0; nt < 4; ++nt)
                acc[nt] = __builtin_amdgcn_mfma_f32_16x16x32_f16(ah[kt], whh0f[nt][kt], acc[nt], 0, 0, 0);
        #pragma unroll
        for (int kt = 0; kt < 2; ++kt) {
            half8 axk = kt ? ax1 : ax0;
            #pragma unroll
            for (int nt = 0; nt < 4; ++nt)
                acc[nt] = __builtin_amdgcn_mfma_f32_16x16x32_f16(axk, wif[nt][kt], acc[nt], 0, 0, 0);
        }
        {
            int tn = (t + 1 < T_STEPS) ? t + 1 : t;
            if constexpr (XH) {
                const _Float16* xq = xph + (size_t)tn * (BATCH * DIN);
                nxh0 = *(const half8*)(xq); nxh1 = *(const half8*)(xq + 32);
            } else {
                const float* xq = xpf + (size_t)tn * (BATCH * DIN);
                nxf0 = *(const f32x4*)(xq);      nxf1 = *(const f32x4*)(xq + 4);
                nxf2 = *(const f32x4*)(xq + 32); nxf3 = *(const f32x4*)(xq + 36);
            }
        }
        #pragma unroll
        for (int i = 0; i < 4; ++i) {
            float ig = sig2(acc[0][i]);
            float fg = sig2(acc[1][i]);
            float gg = tanh2(acc[2][i]);
            float og = sig2(acc[3][i]);
            float c  = fg * c0[i] + ig * gg;
            c0[i] = c;
            h0b[cbo + w0off[i]] = (_Float16)(og * tanh_c(c));
        }
        __syncthreads();

        #pragma unroll
        for (int nt = 0; nt < 4; ++nt) {
            f32x4 b = {bias1[nt], bias1[nt], bias1[nt], bias1[nt]};
            acc[nt] = b;
        }
        #pragma unroll
        for (int kt = 0; kt < 4; ++kt) {
            half8 a0 = *(const half8*)(h0b + cbo + hoff[kt]);
            half8 a1 = *(const half8*)(h1b + pbo + hoff[kt]);
            #pragma unroll
            for (int nt = 0; nt < 4; ++nt)
                acc[nt] = __builtin_amdgcn_mfma_f32_16x16x32_f16(a0, wih1f[nt][kt], acc[nt], 0, 0, 0);
            #pragma unroll
            for (int nt = 0; nt < 4; ++nt) {
                half8 bfr = *(const half8*)(whh1 + nt * 16384 + j0 * 128 + swz[kt]);
                acc[nt] = __builtin_amdgcn_mfma_f32_16x16x32_f16(a1, bfr, acc[nt], 0, 0, 0);
            }
        }
        #pragma unroll
        for (int i = 0; i < 4; ++i) {
            float ig = sig2(acc[0][i]);
            float fg = sig2(acc[1][i]);
            float gg = tanh2(acc[2][i]);
            float og = sig2(acc[3][i]);
            float c  = fg * c1[i] + ig * gg;
            c1[i] = c;
            h1b[cbo + w0off[i]] = (_Float16)(og * tanh_c(c));
        }
        if (w == 7) {
            f32x4 vh = {0.f, 0.f, 0.f, 0.f};
            #pragma unroll
            for (int kt = 0; kt < 4; ++kt) {
                half8 a1 = *(const half8*)(h1b + pbo + hoff[kt]);
                half8 bw = *(const half8*)(woutl + kt * 32 + quad * 8);
                if (col != 0) {
                    #pragma unroll
                    for (int jj = 0; jj < 8; ++jj) bw[jj] = (_Float16)0.0f;
                }
                vh = __builtin_amdgcn_mfma_f32_16x16x32_f16(a1, bw, vh, 0, 0, 0);
            }
            if (t > 0 && col == 0) {
                f32x4 vo = {vh[0] + bout, vh[1] + bout, vh[2] + bout, vh[3] + bout};
                *(f32x4*)(out + (size_t)(t - 1) * BATCH + rowbase + quad * 4) = vo;
            }
        }
    }
    __syncthreads();
    if (w == 7) {
        const int fbo = (((T_STEPS - 1) & 1) ^ 1) * 2048;
        f32x4 vh = {0.f, 0.f, 0.f, 0.f};
        #pragma unroll
        for (int kt = 0; kt < 4; ++kt) {
            half8 a1 = *(const half8*)(h1b + fbo + hoff[kt]);
            half8 bw = *(const half8*)(woutl + kt * 32 + quad * 8);
            if (col != 0) {
                #pragma unroll
                for (int jj = 0; jj < 8; ++jj) bw[jj] = (_Float16)0.0f;
            }
            vh = __builtin_amdgcn_mfma_f32_16x16x32_f16(a1, bw, vh, 0, 0, 0);
        }
        if (col == 0) {
            f32x4 vo = {vh[0] + bout, vh[1] + bout, vh[2] + bout, vh[3] + bout};
            *(f32x4*)(out + (size_t)(T_STEPS - 1) * BATCH + rowbase + quad * 4) = vo;
        }
    }
}

extern "C" void kernel_launch(void* const* d_in, const int* in_sizes, int n_in,
                              void* d_out, int out_size, void* d_ws, size_t ws_size,
                              hipStream_t stream) {
    const float* state = (const float*)d_in[0];
    const float* wih0  = (const float*)d_in[1];
    const float* whh0  = (const float*)d_in[2];
    const float* bih0  = (const float*)d_in[3];
    const float* bhh0  = (const float*)d_in[4];
    const float* wih1  = (const float*)d_in[5];
    const float* whh1  = (const float*)d_in[6];
    const float* bih1  = (const float*)d_in[7];
    const float* bhh1  = (const float*)d_in[8];
    const float* wout  = (const float*)d_in[9];
    const float* bout  = (const float*)d_in[10];
    _Float16* wsh = (_Float16*)d_ws;
    float* outp = (float*)d_out;

    prep_weights<<<896, 256, 0, stream>>>(wih0, whh0, wih1, whh1, wsh);

    if (ws_size >= WS2_TOTAL) {
        prep_state<<<4096, 256, 0, stream>>>(state, wsh + WH_X2);
        lstm_pipe<true><<<32, 512, PIPE_LDS_BYTES, stream>>>(
            state, wsh, bih0, bhh0, bih1, bhh1, wout, bout,
            wsh + WH_SLAB2, (int*)((char*)d_ws + WB_FLAG2), wsh + WH_X2, outp);
    } else if (ws_size >= WS1_TOTAL) {
        lstm_pipe<false><<<32, 512, PIPE_LDS_BYTES, stream>>>(
            state, wsh, bih0, bhh0, bih1, bhh1, wout, bout,
            wsh + WH_SLAB1, (int*)((char*)d_ws + WB_FLAG1), nullptr, outp);
    } else if (ws_size >= WS0XH_TOTAL) {
        prep_state<<<4096, 256, 0, stream>>>(state, wsh + WH_X2);
        lstm_mono<true><<<16, 512, MONO_LDS_BYTES, stream>>>(
            state, wsh, bih0, bhh0, bih1, bhh1, wout, bout, outp);
    } else {
        lstm_mono<false><<<16, 512, MONO_LDS_BYTES, stream>>>(
            state, wsh, bih0, bhh0, bih1, bhh1, wout, bout, outp);
    }
}